// Round 1
// baseline (256.873 us; speedup 1.0000x reference)
//
#include <hip/hip_runtime.h>
#include <hip/hip_bf16.h>
#include <stdint.h>

#define BATCH   4096
#define T_DIM   1024
#define NSTATE  64
#define NITER   341          // (T_DIM-1)/3 == 1023/3
#define PSTR    72           // padded LDS row stride (bf16 elems): 144B, 16B-aligned

typedef short  bf16x8 __attribute__((ext_vector_type(8)));
typedef float  f32x4  __attribute__((ext_vector_type(4)));

// d_ws layout (needs 786944 B)
#define WS_AT     0                       // bf16 AT[8][64][64] : AT[m][s][i] = M_m[i][s]
#define WS_PIE    65536                   // float piE[2][64]   : pi[s]*E[s][o]
#define WS_YPACK  66048                   // u64 ypack[22][BATCH], nibble n of word w = 3 bits of iter w*16+n

// ---------------------------------------------------------------------------
// Pre-kernel: 8 blocks, block m builds M_m = T_{b1} T_{b2} T_{b3} (prob space)
// and stores it TRANSPOSED in bf16.  Block 0 also builds piE and zeroes out.
// ---------------------------------------------------------------------------
__global__ __launch_bounds__(256) void hmm_pre(
    const float* __restrict__ Tmat, const float* __restrict__ Emat,
    const float* __restrict__ Pi, unsigned char* __restrict__ ws,
    float* __restrict__ out)
{
    __shared__ float sT [64][64];
    __shared__ float sT0[64][64];
    __shared__ float sT1[64][64];
    __shared__ float sP2[64][64];
    __shared__ float sE[2][64];
    const int tid = threadIdx.x;
    const int m   = blockIdx.x;            // 0..7

    if (tid < 64) {                        // row softmax of T, emission softmax
        const int r = tid;
        float mx = -1e30f;
        for (int j = 0; j < 64; j++) mx = fmaxf(mx, Tmat[r*64+j]);
        float z = 0.f;
        for (int j = 0; j < 64; j++) z += __expf(Tmat[r*64+j] - mx);
        const float inv = 1.0f / z;
        for (int j = 0; j < 64; j++) sT[r][j] = __expf(Tmat[r*64+j] - mx) * inv;
        const float e0 = Emat[r*2+0], e1 = Emat[r*2+1];
        const float em = fmaxf(e0, e1);
        const float p0 = __expf(e0-em), p1 = __expf(e1-em);
        const float ez = 1.0f / (p0 + p1);
        sE[0][r] = p0 * ez;  sE[1][r] = p1 * ez;
    }
    __syncthreads();

    for (int k = tid; k < 4096; k += 256) {   // T_y = T * diag(E[:,y])
        const int i = k >> 6, j = k & 63;
        const float t = sT[i][j];
        sT0[i][j] = t * sE[0][j];
        sT1[i][j] = t * sE[1][j];
    }
    __syncthreads();

    const int b1 = (m >> 2) & 1, b2 = (m >> 1) & 1, b3 = m & 1;
    const float (*A2)[64] = b2 ? sT1 : sT0;
    const float (*A3)[64] = b3 ? sT1 : sT0;
    for (int k = tid; k < 4096; k += 256) {   // P2 = T_{b2} * T_{b3}
        const int i = k >> 6, j = k & 63;
        float acc = 0.f;
        for (int q = 0; q < 64; q++) acc += A2[i][q] * A3[q][j];
        sP2[i][j] = acc;
    }
    __syncthreads();

    const float (*A1)[64] = b1 ? sT1 : sT0;
    __hip_bfloat16* AT = (__hip_bfloat16*)(ws + WS_AT);
    for (int k = tid; k < 4096; k += 256) {   // M = T_{b1} * P2, store transposed
        const int i = k >> 6, j = k & 63;
        float acc = 0.f;
        for (int q = 0; q < 64; q++) acc += A1[i][q] * sP2[q][j];
        AT[(m*64 + j)*64 + i] = __float2bfloat16(acc);
    }

    if (m == 0 && tid == 0) {                 // piE + zero output accumulator
        float mx = -1e30f;
        for (int s = 0; s < 64; s++) mx = fmaxf(mx, Pi[s]);
        float z = 0.f;
        for (int s = 0; s < 64; s++) z += __expf(Pi[s] - mx);
        const float inv = 1.0f / z;
        float* piE = (float*)(ws + WS_PIE);
        for (int s = 0; s < 64; s++) {
            const float p = __expf(Pi[s] - mx) * inv;
            piE[s]      = p * sE[0][s];
            piE[64 + s] = p * sE[1][s];
        }
        *out = 0.f;
    }
}

// ---------------------------------------------------------------------------
// Pack y into 3-bit-per-iter nibbles: ypack[w][b] holds iters w*16..w*16+15.
// nibble = y(3i+1)<<2 | y(3i+2)<<1 | y(3i+3)  (== matrix index m)
// ---------------------------------------------------------------------------
__global__ __launch_bounds__(256) void hmm_packy(
    const int* __restrict__ y, unsigned long long* __restrict__ ypack)
{
    __shared__ unsigned long long words[4][16];
    const int wave = threadIdx.x >> 6;
    const int lane = threadIdx.x & 63;
    const int row  = blockIdx.x * 4 + wave;
    const int* yr = y + (size_t)row * T_DIM;
    for (int c = 0; c < 16; c++) {
        const int v = yr[c*64 + lane];
        const unsigned long long b = __ballot(v != 0);
        if (lane == 0) words[wave][c] = b;
    }
    __syncthreads();
    const int w = lane;
    if (w < 22) {
        unsigned long long outw = 0ull;
        for (int n = 0; n < 16; n++) {
            const int i = w*16 + n;
            if (i < NITER) {
                const int t1 = 3*i + 1;
                const unsigned long long bA = (words[wave][(t1  )>>6] >> ((t1  ) & 63)) & 1ull;
                const unsigned long long bB = (words[wave][(t1+1)>>6] >> ((t1+1) & 63)) & 1ull;
                const unsigned long long bC = (words[wave][(t1+2)>>6] >> ((t1+2) & 63)) & 1ull;
                outw |= ((bA<<2) | (bB<<1) | bC) << (4*n);
            }
        }
        ypack[(size_t)w * BATCH + row] = outw;
    }
}

// ---------------------------------------------------------------------------
// Main kernel: 256 wgs x 256 thr. wg = 16 batch rows; wave w = state M-tile
// [16w,16w+16). Per iter (3 time steps): 8 candidate MFMAs D_m = M_m^T P^T,
// per-row 3-bit select, renorm every 4 iters, bf16 write-back to LDS.
// ---------------------------------------------------------------------------
__global__ __launch_bounds__(256, 1) void hmm_main(
    const int* __restrict__ y, const unsigned char* __restrict__ ws,
    float* __restrict__ out)
{
    __shared__ __align__(16) __hip_bfloat16 P[2][16*PSTR];
    __shared__ float part[4][16];
    __shared__ float cacc[16];
    __shared__ float logsum[16];

    const int tid  = threadIdx.x;
    const int wv   = tid >> 6;
    const int lane = tid & 63;
    const int bcol = lane & 15;        // batch row within block (B/D col)
    const int g    = lane >> 4;        // lane k-group
    const int R0   = blockIdx.x * 16;

    const __hip_bfloat16* AT = (const __hip_bfloat16*)(ws + WS_AT);
    const float* piE = (const float*)(ws + WS_PIE);
    const unsigned long long* ypack = (const unsigned long long*)(ws + WS_YPACK);

    // A-frags: 8 matrices x 2 K-halves, element (g,j) = M_m[32h+8g+j][s], s = 16wv + (lane&15)
    bf16x8 Afr[8][2];
    {
        const int s = wv*16 + bcol;
        #pragma unroll
        for (int m = 0; m < 8; m++)
            #pragma unroll
            for (int h = 0; h < 2; h++)
                Afr[m][h] = *(const bf16x8*)(AT + ((m*64 + s)*64) + h*32 + g*8);
    }

    if (tid < 16) cacc[tid] = 0.f;
    {   // alpha0[b,s] = pi[s]*E[s][y_b0]
        const int b  = tid >> 4;
        const int s4 = (tid & 15) * 4;
        const int y0 = y[(size_t)(R0 + b) * T_DIM];
        const float* pe = piE + y0*64;
        __hip_bfloat16* dst = &P[0][b*PSTR + s4];
        dst[0] = __float2bfloat16(pe[s4+0]);
        dst[1] = __float2bfloat16(pe[s4+1]);
        dst[2] = __float2bfloat16(pe[s4+2]);
        dst[3] = __float2bfloat16(pe[s4+3]);
    }
    __syncthreads();

    unsigned long long yw = 0ull;
    int cur = 0;
    f32x4 D = {0.f, 0.f, 0.f, 0.f};
    const f32x4 zero = {0.f, 0.f, 0.f, 0.f};

    for (int i = 0; i < NITER; i++) {
        if ((i & 15) == 0) yw = ypack[(size_t)(i >> 4) * BATCH + R0 + bcol];
        const int idx = (int)((yw >> ((i & 15) * 4)) & 7ull);

        // B-frags: contiguous bf16x8 from this row of P
        const __hip_bfloat16* prow = &P[cur][bcol * PSTR];
        const bf16x8 B0 = *(const bf16x8*)(prow + g*8);
        const bf16x8 B1 = *(const bf16x8*)(prow + 32 + g*8);

        // 8 candidate products
        f32x4 cand[8];
        #pragma unroll
        for (int m = 0; m < 8; m++) {
            f32x4 a = __builtin_amdgcn_mfma_f32_16x16x32_bf16(Afr[m][0], B0, zero, 0, 0, 0);
            cand[m]  = __builtin_amdgcn_mfma_f32_16x16x32_bf16(Afr[m][1], B1, a,    0, 0, 0);
        }

        // per-row 3-bit select (28 cndmask)
        const bool s1 = idx & 1, s2 = idx & 2, s4b = idx & 4;
        const f32x4 t0 = s1 ? cand[1] : cand[0];
        const f32x4 t1 = s1 ? cand[3] : cand[2];
        const f32x4 t2 = s1 ? cand[5] : cand[4];
        const f32x4 t3 = s1 ? cand[7] : cand[6];
        const f32x4 u0 = s2 ? t1 : t0;
        const f32x4 u1 = s2 ? t3 : t2;
        D = s4b ? u1 : u0;

        if ((i & 3) == 3) {                   // renorm every 12 time steps
            float p = D.x + D.y + D.z + D.w;
            p += __shfl_xor(p, 16);
            p += __shfl_xor(p, 32);
            if (lane < 16) part[wv][lane] = p;
            __syncthreads();
            const float Sb = part[0][bcol] + part[1][bcol] + part[2][bcol] + part[3][bcol];
            if (tid < 16) cacc[tid] += __logf(Sb);
            D *= (1.0f / Sb);
        }

        // cvt + write back: lane owns rows s0..s0+3 of P^T column bcol
        {
            const int s0 = wv*16 + g*4;
            union { __hip_bfloat16 h[4]; uint2 u; } pk;
            pk.h[0] = __float2bfloat16(D.x);
            pk.h[1] = __float2bfloat16(D.y);
            pk.h[2] = __float2bfloat16(D.z);
            pk.h[3] = __float2bfloat16(D.w);
            *(uint2*)&P[1 - cur][bcol*PSTR + s0] = pk.u;
        }
        __syncthreads();
        cur ^= 1;
    }

    // final: logprob[b] = cacc[b] + ln(sum_s alpha[b][s]);  D holds last alpha
    float p = D.x + D.y + D.z + D.w;
    p += __shfl_xor(p, 16);
    p += __shfl_xor(p, 32);
    if (lane < 16) part[wv][lane] = p;
    __syncthreads();
    if (tid < 16) {
        const float Sb = part[0][tid] + part[1][tid] + part[2][tid] + part[3][tid];
        logsum[tid] = cacc[tid] + __logf(Sb);
    }
    __syncthreads();
    if (tid == 0) {
        float s = 0.f;
        for (int b = 0; b < 16; b++) s += logsum[b];
        atomicAdd(out, s * (1.0f / BATCH));
    }
}

// ---------------------------------------------------------------------------
extern "C" void kernel_launch(void* const* d_in, const int* in_sizes, int n_in,
                              void* d_out, int out_size, void* d_ws, size_t ws_size,
                              hipStream_t stream) {
    const int*   y  = (const int*)  d_in[0];
    const float* T  = (const float*)d_in[1];
    const float* E  = (const float*)d_in[2];
    const float* Pi = (const float*)d_in[3];
    float* out = (float*)d_out;
    unsigned char* ws = (unsigned char*)d_ws;

    hipLaunchKernelGGL(hmm_pre,   dim3(8),        dim3(256), 0, stream, T, E, Pi, ws, out);
    hipLaunchKernelGGL(hmm_packy, dim3(BATCH/4),  dim3(256), 0, stream, y,
                       (unsigned long long*)(ws + WS_YPACK));
    hipLaunchKernelGGL(hmm_main,  dim3(BATCH/16), dim3(256), 0, stream, y, ws, out);
}